// Round 2
// baseline (563.025 us; speedup 1.0000x reference)
//
#include <hip/hip_runtime.h>
#include <hip/hip_bf16.h>

// GCNConv: out = D^-1/2 (A+I) D^-1/2 (X W) + b
// N=100000, E=1600000, IN=128, OUT=64. edge_index is int32 (JAX x64 disabled),
// flat layout [row(1.6M) | col(1.6M)].

#define IN_CH 128
#define OUT_CH 64

// ---------------- degree ----------------
__global__ __launch_bounds__(256) void deg_init_kernel(float* __restrict__ deg, int n) {
    int i = blockIdx.x * 256 + threadIdx.x;
    if (i < n) deg[i] = 1.0f;   // self loop
}

__global__ __launch_bounds__(256) void deg_edges_kernel(const int* __restrict__ col,
                                                        float* __restrict__ deg, int E) {
    int e = blockIdx.x * 256 + threadIdx.x;
    if (e < E) unsafeAtomicAdd(&deg[col[e]], 1.0f);
}

__global__ __launch_bounds__(256) void dinv_kernel(float* __restrict__ deg, int n) {
    int i = blockIdx.x * 256 + threadIdx.x;
    if (i < n) deg[i] = rsqrtf(deg[i]);   // deg >= 1 always
}

// ---------------- GEMM: h' = (x @ W) * dinv[row]; out = h' * dinv[row] + b ----
// Block: 256 threads, 64 rows x 64 cols tile. Thread (tr=tid&15, tc=tid>>4)
// computes rows {tr, tr+16, tr+32, tr+48} x cols {4tc..4tc+3}.
// x staged in LDS with XOR-chunk swizzle so b128 reads are 2-way (free).
__device__ __forceinline__ void fma4(float4& a, float s, const float4& v) {
    a.x = fmaf(s, v.x, a.x);
    a.y = fmaf(s, v.y, a.y);
    a.z = fmaf(s, v.z, a.z);
    a.w = fmaf(s, v.w, a.w);
}

__global__ __launch_bounds__(256) void gemm_kernel(
    const float* __restrict__ x, const float* __restrict__ W,
    const float* __restrict__ b, const float* __restrict__ dinv,
    float* __restrict__ hp, float* __restrict__ out, int n)
{
    __shared__ float xl[64 * 128];   // 32 KB, XOR-swizzled float4 chunks
    __shared__ float wl[128 * 64];   // 32 KB, linear k*64+c

    int tid  = threadIdx.x;
    int row0 = blockIdx.x * 64;

    // stage W: 2048 float4
    {
        const float4* wg = (const float4*)W;
        float4* wls = (float4*)wl;
        #pragma unroll
        for (int i = 0; i < 8; ++i) wls[tid + i * 256] = wg[tid + i * 256];
    }
    // stage x: 64 rows x 32 float4-chunks, chunk index XORed with (r&7)
    {
        float4* xls = (float4*)xl;
        #pragma unroll
        for (int i = 0; i < 8; ++i) {
            int f  = tid + i * 256;       // 0..2047
            int r  = f >> 5;              // 0..63
            int c0 = f & 31;              // chunk in row
            int gr = row0 + r;
            float4 v = make_float4(0.f, 0.f, 0.f, 0.f);
            if (gr < n) v = ((const float4*)(x + (size_t)gr * IN_CH))[c0];
            xls[(r << 5) | (c0 ^ (r & 7))] = v;
        }
    }
    __syncthreads();

    int tr = tid & 15;
    int tc = tid >> 4;    // 0..15 -> cols 4tc..4tc+3

    float4 acc0 = {0,0,0,0}, acc1 = {0,0,0,0}, acc2 = {0,0,0,0}, acc3 = {0,0,0,0};
    const float4* xl4 = (const float4*)xl;
    const float4* wl4 = (const float4*)wl;

    #pragma unroll 4
    for (int k4 = 0; k4 < 32; ++k4) {
        int sc = k4 ^ (tr & 7);   // same swizzle for all 4 rows (stride 16)
        float4 xa0 = xl4[((tr     ) << 5) | sc];
        float4 xa1 = xl4[((tr + 16) << 5) | sc];
        float4 xa2 = xl4[((tr + 32) << 5) | sc];
        float4 xa3 = xl4[((tr + 48) << 5) | sc];
        float4 wb0 = wl4[((k4 * 4 + 0) << 4) | tc];
        float4 wb1 = wl4[((k4 * 4 + 1) << 4) | tc];
        float4 wb2 = wl4[((k4 * 4 + 2) << 4) | tc];
        float4 wb3 = wl4[((k4 * 4 + 3) << 4) | tc];

        fma4(acc0, xa0.x, wb0); fma4(acc0, xa0.y, wb1); fma4(acc0, xa0.z, wb2); fma4(acc0, xa0.w, wb3);
        fma4(acc1, xa1.x, wb0); fma4(acc1, xa1.y, wb1); fma4(acc1, xa1.z, wb2); fma4(acc1, xa1.w, wb3);
        fma4(acc2, xa2.x, wb0); fma4(acc2, xa2.y, wb1); fma4(acc2, xa2.z, wb2); fma4(acc2, xa2.w, wb3);
        fma4(acc3, xa3.x, wb0); fma4(acc3, xa3.y, wb1); fma4(acc3, xa3.z, wb2); fma4(acc3, xa3.w, wb3);
    }

    float4 b4 = ((const float4*)b)[tc];

    float4 accs[4] = {acc0, acc1, acc2, acc3};
    #pragma unroll
    for (int i = 0; i < 4; ++i) {
        int gr = row0 + tr + 16 * i;
        if (gr < n) {
            float di = dinv[gr];
            float4 a = accs[i];
            float4 h4 = make_float4(a.x * di, a.y * di, a.z * di, a.w * di);
            ((float4*)(hp  + (size_t)gr * OUT_CH))[tc] = h4;
            float4 o4 = make_float4(h4.x * di + b4.x, h4.y * di + b4.y,
                                    h4.z * di + b4.z, h4.w * di + b4.w);
            ((float4*)(out + (size_t)gr * OUT_CH))[tc] = o4;
        }
    }
}

// ---------------- scatter: out[col] += h'[row] * dinv[col] ------------------
// 64 lanes per edge, one float per lane. Coalesced 256B gather, fp32 HW atomics.
__global__ __launch_bounds__(256) void scatter_kernel(
    const int* __restrict__ row, const int* __restrict__ col,
    const float* __restrict__ hp, const float* __restrict__ dinv,
    float* __restrict__ out, int E)
{
    int t    = blockIdx.x * 256 + threadIdx.x;
    int e    = t >> 6;
    int lane = t & 63;
    if (e >= E) return;
    int r = row[e];
    int c = col[e];
    float s = dinv[c];
    float v = hp[(size_t)r * OUT_CH + lane] * s;
    unsafeAtomicAdd(out + (size_t)c * OUT_CH + lane, v);
}

extern "C" void kernel_launch(void* const* d_in, const int* in_sizes, int n_in,
                              void* d_out, int out_size, void* d_ws, size_t ws_size,
                              hipStream_t stream) {
    const float* x  = (const float*)d_in[0];
    const int*   ei = (const int*)d_in[1];
    const float* W  = (const float*)d_in[2];
    const float* b  = (const float*)d_in[3];
    float*       out = (float*)d_out;

    int n = in_sizes[0] / IN_CH;     // 100000
    int E = in_sizes[1] / 2;         // 1600000
    const int* row = ei;
    const int* col = ei + E;

    float* dinv = (float*)d_ws;                       // n floats (used as deg first)
    float* hp   = dinv + ((n + 127) & ~127);          // n*64 floats

    deg_init_kernel <<<(n + 255) / 256, 256, 0, stream>>>(dinv, n);
    deg_edges_kernel<<<(E + 255) / 256, 256, 0, stream>>>(col, dinv, E);
    dinv_kernel     <<<(n + 255) / 256, 256, 0, stream>>>(dinv, n);
    gemm_kernel     <<<(n + 63) / 64,   256, 0, stream>>>(x, W, b, dinv, hp, out, n);
    scatter_kernel  <<<(E * 64 + 255) / 256, 256, 0, stream>>>(row, col, hp, dinv, out, E);
}

// Round 3
// 381.026 us; speedup vs baseline: 1.4777x; 1.4777x over previous
//
#include <hip/hip_runtime.h>
#include <hip/hip_bf16.h>

// GCNConv: out = D^-1/2 (A+I) D^-1/2 (X W) + b
// N=100000, E=1600000, IN=128, OUT=64. edge_index int32, [row(E) | col(E)].
//
// Pull-mode CSR (no float atomics):
//   1. int degree histogram over col
//   2. two-level exclusive scan -> row_start, cursor
//   3. fill: csr_row[pos++] = row  (int atomics only)
//   4. GEMM: hp = (x @ W) * dinv[row]
//   5. aggregate: out[c] = dinv[c]*(hp[c] + sum_{e->c} hp[row_e]) + b

#define IN_CH 128
#define OUT_CH 64

// ---------------- degree histogram ----------------
__global__ __launch_bounds__(256) void deg_zero_kernel(int* __restrict__ deg, int n) {
    int i = blockIdx.x * 256 + threadIdx.x;
    if (i < n) deg[i] = 0;
}

__global__ __launch_bounds__(256) void deg_hist_kernel(const int* __restrict__ col,
                                                       int* __restrict__ deg, int E) {
    int e = blockIdx.x * 256 + threadIdx.x;
    if (e < E) atomicAdd(&deg[col[e]], 1);
}

__global__ __launch_bounds__(256) void dinv_kernel(const int* __restrict__ deg,
                                                   float* __restrict__ dinv, int n) {
    int i = blockIdx.x * 256 + threadIdx.x;
    if (i < n) dinv[i] = rsqrtf((float)(deg[i] + 1));   // +1 self loop
}

// ---------------- two-level exclusive scan ----------------
__global__ __launch_bounds__(256) void scan1_kernel(const int* __restrict__ deg,
                                                    int* __restrict__ partial, int n) {
    __shared__ int s[256];
    int tid = threadIdx.x;
    int i   = blockIdx.x * 256 + tid;
    int v   = (i < n) ? deg[i] : 0;
    s[tid] = v; __syncthreads();
    #pragma unroll
    for (int off = 1; off < 256; off <<= 1) {
        int t = (tid >= off) ? s[tid - off] : 0;
        __syncthreads();
        s[tid] += t;
        __syncthreads();
    }
    if (tid == 255) partial[blockIdx.x] = s[255];
}

// single block, nb <= 512
__global__ __launch_bounds__(512) void scan2_kernel(int* __restrict__ partial, int nb) {
    __shared__ int s[512];
    int tid = threadIdx.x;
    int v   = (tid < nb) ? partial[tid] : 0;
    s[tid] = v; __syncthreads();
    #pragma unroll
    for (int off = 1; off < 512; off <<= 1) {
        int t = (tid >= off) ? s[tid - off] : 0;
        __syncthreads();
        s[tid] += t;
        __syncthreads();
    }
    if (tid < nb) partial[tid] = s[tid] - v;   // exclusive
}

__global__ __launch_bounds__(256) void scan3_kernel(const int* __restrict__ deg,
                                                    const int* __restrict__ partial,
                                                    int* __restrict__ row_start,
                                                    int* __restrict__ cursor,
                                                    int n, int E) {
    __shared__ int s[256];
    int tid = threadIdx.x;
    int i   = blockIdx.x * 256 + tid;
    int v   = (i < n) ? deg[i] : 0;
    s[tid] = v; __syncthreads();
    #pragma unroll
    for (int off = 1; off < 256; off <<= 1) {
        int t = (tid >= off) ? s[tid - off] : 0;
        __syncthreads();
        s[tid] += t;
        __syncthreads();
    }
    if (i < n) {
        int start = partial[blockIdx.x] + s[tid] - v;  // exclusive
        row_start[i] = start;
        cursor[i]    = start;
    }
    if (blockIdx.x == 0 && tid == 0) row_start[n] = E;
}

// ---------------- CSR fill (counting-sort scatter) ----------------
__global__ __launch_bounds__(256) void fill_kernel(const int* __restrict__ row,
                                                   const int* __restrict__ col,
                                                   int* __restrict__ cursor,
                                                   int* __restrict__ csr_row, int E) {
    int e = blockIdx.x * 256 + threadIdx.x;
    if (e < E) {
        int c = col[e];
        int p = atomicAdd(&cursor[c], 1);
        csr_row[p] = row[e];
    }
}

// ---------------- GEMM: hp = (x @ W) * dinv[row] ----------------
__device__ __forceinline__ void fma4(float4& a, float s, const float4& v) {
    a.x = fmaf(s, v.x, a.x);
    a.y = fmaf(s, v.y, a.y);
    a.z = fmaf(s, v.z, a.z);
    a.w = fmaf(s, v.w, a.w);
}

__global__ __launch_bounds__(256) void gemm_kernel(
    const float* __restrict__ x, const float* __restrict__ W,
    const float* __restrict__ dinv, float* __restrict__ hp, int n)
{
    __shared__ float xl[64 * 128];   // 32 KB, XOR-swizzled float4 chunks
    __shared__ float wl[128 * 64];   // 32 KB, linear k*64+c

    int tid  = threadIdx.x;
    int row0 = blockIdx.x * 64;

    {
        const float4* wg = (const float4*)W;
        float4* wls = (float4*)wl;
        #pragma unroll
        for (int i = 0; i < 8; ++i) wls[tid + i * 256] = wg[tid + i * 256];
    }
    {
        float4* xls = (float4*)xl;
        #pragma unroll
        for (int i = 0; i < 8; ++i) {
            int f  = tid + i * 256;
            int r  = f >> 5;
            int c0 = f & 31;
            int gr = row0 + r;
            float4 v = make_float4(0.f, 0.f, 0.f, 0.f);
            if (gr < n) v = ((const float4*)(x + (size_t)gr * IN_CH))[c0];
            xls[(r << 5) | (c0 ^ (r & 7))] = v;
        }
    }
    __syncthreads();

    int tr = tid & 15;
    int tc = tid >> 4;

    float4 acc0 = {0,0,0,0}, acc1 = {0,0,0,0}, acc2 = {0,0,0,0}, acc3 = {0,0,0,0};
    const float4* xl4 = (const float4*)xl;
    const float4* wl4 = (const float4*)wl;

    #pragma unroll 4
    for (int k4 = 0; k4 < 32; ++k4) {
        int sc = k4 ^ (tr & 7);
        float4 xa0 = xl4[((tr     ) << 5) | sc];
        float4 xa1 = xl4[((tr + 16) << 5) | sc];
        float4 xa2 = xl4[((tr + 32) << 5) | sc];
        float4 xa3 = xl4[((tr + 48) << 5) | sc];
        float4 wb0 = wl4[((k4 * 4 + 0) << 4) | tc];
        float4 wb1 = wl4[((k4 * 4 + 1) << 4) | tc];
        float4 wb2 = wl4[((k4 * 4 + 2) << 4) | tc];
        float4 wb3 = wl4[((k4 * 4 + 3) << 4) | tc];

        fma4(acc0, xa0.x, wb0); fma4(acc0, xa0.y, wb1); fma4(acc0, xa0.z, wb2); fma4(acc0, xa0.w, wb3);
        fma4(acc1, xa1.x, wb0); fma4(acc1, xa1.y, wb1); fma4(acc1, xa1.z, wb2); fma4(acc1, xa1.w, wb3);
        fma4(acc2, xa2.x, wb0); fma4(acc2, xa2.y, wb1); fma4(acc2, xa2.z, wb2); fma4(acc2, xa2.w, wb3);
        fma4(acc3, xa3.x, wb0); fma4(acc3, xa3.y, wb1); fma4(acc3, xa3.z, wb2); fma4(acc3, xa3.w, wb3);
    }

    float4 accs[4] = {acc0, acc1, acc2, acc3};
    #pragma unroll
    for (int i = 0; i < 4; ++i) {
        int gr = row0 + tr + 16 * i;
        if (gr < n) {
            float di = dinv[gr];
            float4 a = accs[i];
            float4 h4 = make_float4(a.x * di, a.y * di, a.z * di, a.w * di);
            ((float4*)(hp + (size_t)gr * OUT_CH))[tc] = h4;
        }
    }
}

// ---------------- aggregate: out[c] = dinv[c]*(hp[c] + sum hp[r]) + b -------
// One wave per node. Lane = channel. Edge indices loaded 64-wide, broadcast
// via shfl; hp gathers are 256B coalesced per wave, L3-resident.
__global__ __launch_bounds__(256) void aggregate_kernel(
    const int* __restrict__ row_start, const int* __restrict__ csr_row,
    const float* __restrict__ hp, const float* __restrict__ dinv,
    const float* __restrict__ b, float* __restrict__ out, int n)
{
    int wid  = (blockIdx.x * 256 + threadIdx.x) >> 6;   // node id
    int lane = threadIdx.x & 63;
    if (wid >= n) return;

    int s0 = row_start[wid];
    int s1 = row_start[wid + 1];

    float self = hp[(size_t)wid * OUT_CH + lane];
    float a0 = 0.f, a1 = 0.f, a2 = 0.f, a3 = 0.f;

    for (int base = s0; base < s1; base += 64) {
        int cnt  = min(64, s1 - base);
        int ridx = (base + lane < s1) ? csr_row[base + lane] : 0;
        int j = 0;
        for (; j + 4 <= cnt; j += 4) {
            int r0 = __shfl(ridx, j);
            int r1 = __shfl(ridx, j + 1);
            int r2 = __shfl(ridx, j + 2);
            int r3 = __shfl(ridx, j + 3);
            a0 += hp[(size_t)r0 * OUT_CH + lane];
            a1 += hp[(size_t)r1 * OUT_CH + lane];
            a2 += hp[(size_t)r2 * OUT_CH + lane];
            a3 += hp[(size_t)r3 * OUT_CH + lane];
        }
        for (; j < cnt; ++j) {
            int r = __shfl(ridx, j);
            a0 += hp[(size_t)r * OUT_CH + lane];
        }
    }
    float acc = self + ((a0 + a1) + (a2 + a3));
    out[(size_t)wid * OUT_CH + lane] = fmaf(dinv[wid], acc, b[lane]);
}

extern "C" void kernel_launch(void* const* d_in, const int* in_sizes, int n_in,
                              void* d_out, int out_size, void* d_ws, size_t ws_size,
                              hipStream_t stream) {
    const float* x  = (const float*)d_in[0];
    const int*   ei = (const int*)d_in[1];
    const float* W  = (const float*)d_in[2];
    const float* b  = (const float*)d_in[3];
    float*       out = (float*)d_out;

    int n = in_sizes[0] / IN_CH;     // 100000
    int E = in_sizes[1] / 2;         // 1600000
    const int* row = ei;
    const int* col = ei + E;

    int nb = (n + 255) / 256;        // 391 (must be <= 512)

    // workspace layout (4B units), hp 256B-aligned at the end
    char* ws = (char*)d_ws;
    int*   deg       = (int*)ws;                 ws += (size_t)n * 4;
    float* dinv      = (float*)ws;               ws += (size_t)n * 4;
    int*   row_start = (int*)ws;                 ws += (size_t)(n + 1) * 4;
    int*   cursor    = (int*)ws;                 ws += (size_t)n * 4;
    int*   partial   = (int*)ws;                 ws += 512 * 4;
    int*   csr_row   = (int*)ws;                 ws += (size_t)E * 4;
    ws = (char*)(((uintptr_t)ws + 255) & ~(uintptr_t)255);
    float* hp        = (float*)ws;

    deg_zero_kernel <<<nb, 256, 0, stream>>>(deg, n);
    deg_hist_kernel <<<(E + 255) / 256, 256, 0, stream>>>(col, deg, E);
    dinv_kernel     <<<nb, 256, 0, stream>>>(deg, dinv, n);
    scan1_kernel    <<<nb, 256, 0, stream>>>(deg, partial, n);
    scan2_kernel    <<<1, 512, 0, stream>>>(partial, nb);
    scan3_kernel    <<<nb, 256, 0, stream>>>(deg, partial, row_start, cursor, n, E);
    fill_kernel     <<<(E + 255) / 256, 256, 0, stream>>>(row, col, cursor, csr_row, E);
    gemm_kernel     <<<(n + 63) / 64, 256, 0, stream>>>(x, W, dinv, hp, n);
    aggregate_kernel<<<(n + 3) / 4, 256, 0, stream>>>(row_start, csr_row, hp, dinv, b, out, n);
}

// Round 4
// 363.750 us; speedup vs baseline: 1.5478x; 1.0475x over previous
//
#include <hip/hip_runtime.h>
#include <hip/hip_bf16.h>

// GCNConv: out = D^-1/2 (A+I) D^-1/2 (X W) + b
// N=100000, E=1600000, IN=128, OUT=64. edge_index int32, [row(E) | col(E)].
//
// Pipeline (no float atomics, write-coalesced CSR build):
//   1. int degree histogram over col
//   2. two-level exclusive scan -> row_start
//   3. pass A: partition packed (row | lcol<<17) into 128-node buckets
//              (bucket offsets = row_start[b*128], line-padded cursors)
//   4. pass B: per-bucket LDS-cursor scatter -> csr_row (8 KB window, L2)
//   5. GEMM: hp = (x @ W) * dinv[row]        (hp overlays pairs)
//   6. aggregate: out[c] = dinv[c]*(hp[c] + sum_{e->c} hp[row_e]) + b

#define IN_CH 128
#define OUT_CH 64
#define BSHIFT 7            // 128 nodes per bucket
#define BNODES 128

// ---------------- degree histogram ----------------
__global__ __launch_bounds__(256) void deg_zero_kernel(int* __restrict__ deg, int n) {
    int i = blockIdx.x * 256 + threadIdx.x;
    if (i < n) deg[i] = 0;
}

__global__ __launch_bounds__(256) void deg_hist_kernel(const int* __restrict__ col,
                                                       int* __restrict__ deg, int E) {
    int e = blockIdx.x * 256 + threadIdx.x;
    if (e < E) atomicAdd(&deg[col[e]], 1);
}

__global__ __launch_bounds__(256) void dinv_kernel(const int* __restrict__ deg,
                                                   float* __restrict__ dinv, int n) {
    int i = blockIdx.x * 256 + threadIdx.x;
    if (i < n) dinv[i] = rsqrtf((float)(deg[i] + 1));   // +1 self loop
}

// ---------------- two-level exclusive scan ----------------
__global__ __launch_bounds__(256) void scan1_kernel(const int* __restrict__ deg,
                                                    int* __restrict__ partial, int n) {
    __shared__ int s[256];
    int tid = threadIdx.x;
    int i   = blockIdx.x * 256 + tid;
    int v   = (i < n) ? deg[i] : 0;
    s[tid] = v; __syncthreads();
    #pragma unroll
    for (int off = 1; off < 256; off <<= 1) {
        int t = (tid >= off) ? s[tid - off] : 0;
        __syncthreads();
        s[tid] += t;
        __syncthreads();
    }
    if (tid == 255) partial[blockIdx.x] = s[255];
}

// single block, nb <= 512
__global__ __launch_bounds__(512) void scan2_kernel(int* __restrict__ partial, int nb) {
    __shared__ int s[512];
    int tid = threadIdx.x;
    int v   = (tid < nb) ? partial[tid] : 0;
    s[tid] = v; __syncthreads();
    #pragma unroll
    for (int off = 1; off < 512; off <<= 1) {
        int t = (tid >= off) ? s[tid - off] : 0;
        __syncthreads();
        s[tid] += t;
        __syncthreads();
    }
    if (tid < nb) partial[tid] = s[tid] - v;   // exclusive
}

__global__ __launch_bounds__(256) void scan3_kernel(const int* __restrict__ deg,
                                                    const int* __restrict__ partial,
                                                    int* __restrict__ row_start,
                                                    int n, int E) {
    __shared__ int s[256];
    int tid = threadIdx.x;
    int i   = blockIdx.x * 256 + tid;
    int v   = (i < n) ? deg[i] : 0;
    s[tid] = v; __syncthreads();
    #pragma unroll
    for (int off = 1; off < 256; off <<= 1) {
        int t = (tid >= off) ? s[tid - off] : 0;
        __syncthreads();
        s[tid] += t;
        __syncthreads();
    }
    if (i < n) row_start[i] = partial[blockIdx.x] + s[tid] - v;  // exclusive
    if (blockIdx.x == 0 && tid == 0) row_start[n] = E;
}

// ---------------- bucket cursors (one per 64B line) ----------------
__global__ __launch_bounds__(256) void bcur_init_kernel(const int* __restrict__ row_start,
                                                        int* __restrict__ bcur,
                                                        int NB, int n) {
    int i = blockIdx.x * 256 + threadIdx.x;
    if (i < NB) bcur[i << 4] = row_start[min(i << BSHIFT, n)];
}

// ---------------- pass A: partition into buckets (packed 4B records) --------
__global__ __launch_bounds__(256) void partition_kernel(const int* __restrict__ row,
                                                        const int* __restrict__ col,
                                                        int* __restrict__ bcur,
                                                        int* __restrict__ pairs, int E) {
    int e = blockIdx.x * 256 + threadIdx.x;
    if (e < E) {
        int c = col[e];
        int b = c >> BSHIFT;
        int pos = atomicAdd(&bcur[b << 4], 1);
        pairs[pos] = row[e] | ((c & (BNODES - 1)) << 17);   // n < 2^17
    }
}

// ---------------- pass B: per-bucket scatter -> csr_row ---------------------
__global__ __launch_bounds__(256) void bucket_fill_kernel(const int* __restrict__ row_start,
                                                          const int* __restrict__ pairs,
                                                          int* __restrict__ csr_row, int n) {
    __shared__ int lcur[BNODES];
    int b     = blockIdx.x;
    int node0 = b << BSHIFT;
    int tid   = threadIdx.x;
    int nodeCnt = min(BNODES, n - node0);
    if (tid < nodeCnt) lcur[tid] = row_start[node0 + tid];
    __syncthreads();
    int pstart = row_start[node0];
    int pend   = row_start[min(node0 + BNODES, n)];
    for (int e = pstart + tid; e < pend; e += 256) {
        int p   = pairs[e];
        int r   = p & 0x1FFFF;
        int lc  = p >> 17;
        int pos = atomicAdd(&lcur[lc], 1);
        csr_row[pos] = r;
    }
}

// ---------------- GEMM: hp = (x @ W) * dinv[row] ----------------
__device__ __forceinline__ void fma4(float4& a, float s, const float4& v) {
    a.x = fmaf(s, v.x, a.x);
    a.y = fmaf(s, v.y, a.y);
    a.z = fmaf(s, v.z, a.z);
    a.w = fmaf(s, v.w, a.w);
}

__global__ __launch_bounds__(256) void gemm_kernel(
    const float* __restrict__ x, const float* __restrict__ W,
    const float* __restrict__ dinv, float* __restrict__ hp, int n)
{
    __shared__ float xl[64 * 128];   // 32 KB, XOR-swizzled float4 chunks
    __shared__ float wl[128 * 64];   // 32 KB, linear k*64+c

    int tid  = threadIdx.x;
    int row0 = blockIdx.x * 64;

    {
        const float4* wg = (const float4*)W;
        float4* wls = (float4*)wl;
        #pragma unroll
        for (int i = 0; i < 8; ++i) wls[tid + i * 256] = wg[tid + i * 256];
    }
    {
        float4* xls = (float4*)xl;
        #pragma unroll
        for (int i = 0; i < 8; ++i) {
            int f  = tid + i * 256;
            int r  = f >> 5;
            int c0 = f & 31;
            int gr = row0 + r;
            float4 v = make_float4(0.f, 0.f, 0.f, 0.f);
            if (gr < n) v = ((const float4*)(x + (size_t)gr * IN_CH))[c0];
            xls[(r << 5) | (c0 ^ (r & 7))] = v;
        }
    }
    __syncthreads();

    int tr = tid & 15;
    int tc = tid >> 4;

    float4 acc0 = {0,0,0,0}, acc1 = {0,0,0,0}, acc2 = {0,0,0,0}, acc3 = {0,0,0,0};
    const float4* xl4 = (const float4*)xl;
    const float4* wl4 = (const float4*)wl;

    #pragma unroll 4
    for (int k4 = 0; k4 < 32; ++k4) {
        int sc = k4 ^ (tr & 7);
        float4 xa0 = xl4[((tr     ) << 5) | sc];
        float4 xa1 = xl4[((tr + 16) << 5) | sc];
        float4 xa2 = xl4[((tr + 32) << 5) | sc];
        float4 xa3 = xl4[((tr + 48) << 5) | sc];
        float4 wb0 = wl4[((k4 * 4 + 0) << 4) | tc];
        float4 wb1 = wl4[((k4 * 4 + 1) << 4) | tc];
        float4 wb2 = wl4[((k4 * 4 + 2) << 4) | tc];
        float4 wb3 = wl4[((k4 * 4 + 3) << 4) | tc];

        fma4(acc0, xa0.x, wb0); fma4(acc0, xa0.y, wb1); fma4(acc0, xa0.z, wb2); fma4(acc0, xa0.w, wb3);
        fma4(acc1, xa1.x, wb0); fma4(acc1, xa1.y, wb1); fma4(acc1, xa1.z, wb2); fma4(acc1, xa1.w, wb3);
        fma4(acc2, xa2.x, wb0); fma4(acc2, xa2.y, wb1); fma4(acc2, xa2.z, wb2); fma4(acc2, xa2.w, wb3);
        fma4(acc3, xa3.x, wb0); fma4(acc3, xa3.y, wb1); fma4(acc3, xa3.z, wb2); fma4(acc3, xa3.w, wb3);
    }

    float4 accs[4] = {acc0, acc1, acc2, acc3};
    #pragma unroll
    for (int i = 0; i < 4; ++i) {
        int gr = row0 + tr + 16 * i;
        if (gr < n) {
            float di = dinv[gr];
            float4 a = accs[i];
            float4 h4 = make_float4(a.x * di, a.y * di, a.z * di, a.w * di);
            ((float4*)(hp + (size_t)gr * OUT_CH))[tc] = h4;
        }
    }
}

// ---------------- aggregate: out[c] = dinv[c]*(hp[c] + sum hp[r]) + b -------
__global__ __launch_bounds__(256) void aggregate_kernel(
    const int* __restrict__ row_start, const int* __restrict__ csr_row,
    const float* __restrict__ hp, const float* __restrict__ dinv,
    const float* __restrict__ b, float* __restrict__ out, int n)
{
    int wid  = (blockIdx.x * 256 + threadIdx.x) >> 6;   // node id
    int lane = threadIdx.x & 63;
    if (wid >= n) return;

    int s0 = row_start[wid];
    int s1 = row_start[wid + 1];

    float self = hp[(size_t)wid * OUT_CH + lane];
    float a0 = 0.f, a1 = 0.f, a2 = 0.f, a3 = 0.f;

    for (int base = s0; base < s1; base += 64) {
        int cnt  = min(64, s1 - base);
        int ridx = (base + lane < s1) ? csr_row[base + lane] : 0;
        int j = 0;
        for (; j + 4 <= cnt; j += 4) {
            int r0 = __shfl(ridx, j);
            int r1 = __shfl(ridx, j + 1);
            int r2 = __shfl(ridx, j + 2);
            int r3 = __shfl(ridx, j + 3);
            a0 += hp[(size_t)r0 * OUT_CH + lane];
            a1 += hp[(size_t)r1 * OUT_CH + lane];
            a2 += hp[(size_t)r2 * OUT_CH + lane];
            a3 += hp[(size_t)r3 * OUT_CH + lane];
        }
        for (; j < cnt; ++j) {
            int r = __shfl(ridx, j);
            a0 += hp[(size_t)r * OUT_CH + lane];
        }
    }
    float acc = self + ((a0 + a1) + (a2 + a3));
    out[(size_t)wid * OUT_CH + lane] = fmaf(dinv[wid], acc, b[lane]);
}

extern "C" void kernel_launch(void* const* d_in, const int* in_sizes, int n_in,
                              void* d_out, int out_size, void* d_ws, size_t ws_size,
                              hipStream_t stream) {
    const float* x  = (const float*)d_in[0];
    const int*   ei = (const int*)d_in[1];
    const float* W  = (const float*)d_in[2];
    const float* b  = (const float*)d_in[3];
    float*       out = (float*)d_out;

    int n = in_sizes[0] / IN_CH;     // 100000
    int E = in_sizes[1] / 2;         // 1600000
    const int* row = ei;
    const int* col = ei + E;

    int nb = (n + 255) / 256;             // 391 (<= 512)
    int NB = (n + BNODES - 1) >> BSHIFT;  // 782 buckets

    // workspace layout (pairs overlays hp: passB completes before gemm writes hp)
    char* ws = (char*)d_ws;
    int*   deg       = (int*)ws;                 ws += (size_t)n * 4;
    float* dinv      = (float*)ws;               ws += (size_t)n * 4;
    int*   row_start = (int*)ws;                 ws += (size_t)(n + 1) * 4;
    int*   partial   = (int*)ws;                 ws += 512 * 4;
    int*   bcur      = (int*)ws;                 ws += (size_t)NB * 16 * 4;  // line-padded
    int*   csr_row   = (int*)ws;                 ws += (size_t)E * 4;
    ws = (char*)(((uintptr_t)ws + 255) & ~(uintptr_t)255);
    int*   pairs     = (int*)ws;                 // E ints      (phase 1)
    float* hp        = (float*)ws;               // n*64 floats (phase 2, overlays pairs)

    deg_zero_kernel   <<<nb, 256, 0, stream>>>(deg, n);
    deg_hist_kernel   <<<(E + 255) / 256, 256, 0, stream>>>(col, deg, E);
    dinv_kernel       <<<nb, 256, 0, stream>>>(deg, dinv, n);
    scan1_kernel      <<<nb, 256, 0, stream>>>(deg, partial, n);
    scan2_kernel      <<<1, 512, 0, stream>>>(partial, nb);
    scan3_kernel      <<<nb, 256, 0, stream>>>(deg, partial, row_start, n, E);
    bcur_init_kernel  <<<(NB + 255) / 256, 256, 0, stream>>>(row_start, bcur, NB, n);
    partition_kernel  <<<(E + 255) / 256, 256, 0, stream>>>(row, col, bcur, pairs, E);
    bucket_fill_kernel<<<NB, 256, 0, stream>>>(row_start, pairs, csr_row, n);
    gemm_kernel       <<<(n + 63) / 64, 256, 0, stream>>>(x, W, dinv, hp, n);
    aggregate_kernel  <<<(n + 3) / 4, 256, 0, stream>>>(row_start, csr_row, hp, dinv, b, out, n);
}